// Round 4
// baseline (207.098 us; speedup 1.0000x reference)
//
#include <hip/hip_runtime.h>

// y[b,o,p] = sum_c wproj[o,c] * illu[b,c,p] * (sum_i wmix[c,i]*x[b,i,p])
// (attention collapses: DIM==HEADS==64 => softmax over singleton == 1.0;
//  0.6/0.4 output mix commutes onto the weights: wmix = .6*wvs + .4*wvt)
//
// R10 = R9 + tile->block remap (single variable). Evidence: R2/R4/R5/R6/R9
// — five different structures — all pin at 72-75us = 1.9 TB/s with every
// pipe idle and clean traffic (R9: FETCH 69MB, WRITE 71MB, conflicts 0).
// Common factor: all read/write 64-row tiles as 256B-per-row bursts at a
// 256KB power-of-2 stride (channel pitch) -> DRAM channel/bank camping caps
// achievable BW ~1.9 TB/s. Fix: per step t, ALL 1024 blocks process image t,
// block b owning pixel window [b*64, b*64+64) of every row -> the resident
// block set tiles the full image contiguously and sweeps it front-to-back,
// a copy-like sequential stream at DRAM. Per-wave code (fragments, MFMA
// mapping, XH row privacy, T14 prefetch, per-tile raw barrier) is identical
// to R9. Windows are 256B line-aligned: no new cross-block half-lines.
// Per-step working set = one image triple (192MB < 256MB L3).

#define HW 65536
#define CH 64
#define PT 64    // pixels per tile (window per block per step)
#define SX 68    // bf16 row stride: 136B rows, 8B-aligned, bank-spread frags
#define TPB 4    // steps per block == batch images; grid = HW/PT = 1024

typedef short s4_t __attribute__((ext_vector_type(4)));
typedef short s8_t __attribute__((ext_vector_type(8)));
typedef float f4_t __attribute__((ext_vector_type(4)));

static __device__ __forceinline__ unsigned short f2bf(float f) {
  unsigned u = __float_as_uint(f);
  return (unsigned short)((u + 0x7fffu + ((u >> 16) & 1u)) >> 16);  // RNE
}
static __device__ __forceinline__ s8_t ld8(const unsigned short* p) {
  s4_t lo = *(const s4_t*)p;        // rows 8B-aligned: 2x ds_read_b64
  s4_t hi = *(const s4_t*)(p + 4);
  s8_t r = {lo[0], lo[1], lo[2], lo[3], hi[0], hi[1], hi[2], hi[3]};
  return r;
}

__global__ __launch_bounds__(256, 4) void fused_hsattn(
    const float* __restrict__ x, const float* __restrict__ illu,
    const float* __restrict__ wvs, const float* __restrict__ wvt,
    const float* __restrict__ wproj, float* __restrict__ out) {
  __shared__ __align__(16) unsigned short WM[CH * SX];   // 8.5 KB wmix  [c][i]
  __shared__ __align__(16) unsigned short WP[CH * SX];   // 8.5 KB wproj [o][c]
  __shared__ __align__(16) unsigned short XH[PT * SX];   // 8.5 KB u'^T bounce

  const int tid  = threadIdx.x;
  const int lane = tid & 63;
  const int wv   = tid >> 6;
  const int n15  = lane & 15;
  const int q    = lane >> 4;
  const int nb   = wv * 16;                    // wave owns pixels nb..nb+15

  // step t -> image t; this block owns pixel window [pix0, pix0+64) of every
  // row. base(t) = t*CH*HW + pix0 (max ~12.65M floats + 63*HW: fits int).
  const int pix0 = blockIdx.x << 6;
  const int imgs = CH * HW;                    // 4,194,304 floats per image

  // ---- (1) weight loads FIRST (oldest vmcnt slots; L2-hot after wave 1)
  f4_t wa[4], wb[4], wc[4];
#pragma unroll
  for (int it = 0; it < 4; ++it) {
    int j4 = (it * 256 + tid) * 4;
    wa[it] = *(const f4_t*)(wvs + j4);
    wb[it] = *(const f4_t*)(wvt + j4);
    wc[it] = *(const f4_t*)(wproj + j4);
  }

  // ---- (2) step-0 prefetch (younger than weights: the weight-convert
  // vmcnt wait leaves these 32 loads in flight).
  // x frag: lane (q,n15) needs x[k = kc*32+q*8+j][pix nb+n15] -> per inst the
  // wave touches 4 rows x 16 consecutive floats = 4x64B segments (coalesced).
  float xv[16], iv[16];
  {
    const float* xb = x + pix0 + nb + n15;
    const float* ib = illu + pix0 + nb + n15;
#pragma unroll
    for (int kc = 0; kc < 2; ++kc)
#pragma unroll
      for (int j = 0; j < 8; ++j)
        xv[kc * 8 + j] = xb[(kc * 32 + q * 8 + j) * HW];
#pragma unroll
    for (int mt = 0; mt < 4; ++mt)
#pragma unroll
      for (int r = 0; r < 4; ++r)
        iv[mt * 4 + r] = ib[(mt * 16 + q * 4 + r) * HW];
  }

  // ---- (3) convert + stage weights (once per block)
#pragma unroll
  for (int it = 0; it < 4; ++it) {
    int idx = it * 256 + tid;                  // float4 index 0..1023
    int r = idx >> 4, c4 = (idx & 15) * 4;
    s4_t m, w;
#pragma unroll
    for (int j = 0; j < 4; ++j) {
      m[j] = (short)f2bf(0.6f * wa[it][j] + 0.4f * wb[it][j]);
      w[j] = (short)f2bf(wc[it][j]);
    }
    *(s4_t*)(WM + r * SX + c4) = m;
    *(s4_t*)(WP + r * SX + c4) = w;
  }
  __syncthreads();   // publishes WM/WP (the only full barrier)

  // ---- (4) step loop over images: one raw s_barrier per step bounds wave
  // drift so complementary 64B line-halves (waves 0/1, 2/3) merge in L2.
#pragma unroll
  for (int t = 0; t < TPB; ++t) {
    const int base = t * imgs + pix0;

    // B fragments for phase 1 (frees xv for the t+1 prefetch)
    s8_t B0, B1;
#pragma unroll
    for (int j = 0; j < 8; ++j) {
      B0[j] = (short)f2bf(xv[j]);
      B1[j] = (short)f2bf(xv[8 + j]);
    }

    // issue x(t+1) now: load-use distance = phase1+gate+phase2 of step t
    if (t + 1 < TPB) {
      const float* xb = x + (t + 1) * imgs + pix0 + nb + n15;
#pragma unroll
      for (int kc = 0; kc < 2; ++kc)
#pragma unroll
        for (int j = 0; j < 8; ++j)
          xv[kc * 8 + j] = xb[(kc * 32 + q * 8 + j) * HW];
    }

    // phase 1: u = wmix * x   (A[m=n15][k], B[n=pixel n15][k])
    f4_t acc[4];
#pragma unroll
    for (int i = 0; i < 4; ++i) acc[i] = (f4_t){0.f, 0.f, 0.f, 0.f};
#pragma unroll
    for (int mt = 0; mt < 4; ++mt) {
      s8_t A0 = ld8(WM + (mt * 16 + n15) * SX + q * 8);
      acc[mt] = __builtin_amdgcn_mfma_f32_16x16x32_bf16(A0, B0, acc[mt], 0, 0, 0);
      s8_t A1 = ld8(WM + (mt * 16 + n15) * SX + 32 + q * 8);
      acc[mt] = __builtin_amdgcn_mfma_f32_16x16x32_bf16(A1, B1, acc[mt], 0, 0, 0);
    }

    // gate with illu, write u'^T into this wave's private XH rows.
    // C/D layout: row c = mt*16 + q*4 + r, col = pixel nb+n15.
#pragma unroll
    for (int mt = 0; mt < 4; ++mt) {
      s4_t h;
#pragma unroll
      for (int r = 0; r < 4; ++r)
        h[r] = (short)f2bf(acc[mt][r] * iv[mt * 4 + r]);
      *(s4_t*)(XH + (nb + n15) * SX + mt * 16 + q * 4) = h;
    }

    // issue illu(t+1) now (iv consumed by the gate above)
    if (t + 1 < TPB) {
      const float* ib = illu + (t + 1) * imgs + pix0 + nb + n15;
#pragma unroll
      for (int mt = 0; mt < 4; ++mt)
#pragma unroll
        for (int r = 0; r < 4; ++r)
          iv[mt * 4 + r] = ib[(mt * 16 + q * 4 + r) * HW];
    }

    // phase 2: y = wproj * u'  (B from own XH rows; same-wave DS ordered)
    f4_t acc2[4];
#pragma unroll
    for (int i = 0; i < 4; ++i) acc2[i] = (f4_t){0.f, 0.f, 0.f, 0.f};
#pragma unroll
    for (int kc = 0; kc < 2; ++kc) {
      s8_t B = ld8(XH + (nb + n15) * SX + kc * 32 + q * 8);
#pragma unroll
      for (int mt = 0; mt < 4; ++mt) {
        s8_t A = ld8(WP + (mt * 16 + n15) * SX + kc * 32 + q * 8);
        acc2[mt] = __builtin_amdgcn_mfma_f32_16x16x32_bf16(A, B, acc2[mt], 0, 0, 0);
      }
    }

    // store (fire-and-forget; complementary wave halves temporally close)
#pragma unroll
    for (int mt = 0; mt < 4; ++mt) {
      float* op = out + base + (mt * 16 + q * 4) * HW + nb + n15;
      f4_t a = acc2[mt];
#pragma unroll
      for (int r = 0; r < 4; ++r) op[r * HW] = a[r];
    }

    // re-sync waves: raw barrier, NO memory drain (no cross-wave sharing in
    // this loop; XH rows wave-private) -> prefetch loads stay in flight.
    __builtin_amdgcn_s_barrier();
  }
}

extern "C" void kernel_launch(void* const* d_in, const int* in_sizes, int n_in,
                              void* d_out, int out_size, void* d_ws, size_t ws_size,
                              hipStream_t stream) {
  const float* x     = (const float*)d_in[0];   // (4,64,256,256)
  const float* illu  = (const float*)d_in[1];   // (4,64,256,256)
  const float* wvs   = (const float*)d_in[4];   // w_v_spec (64,64)
  const float* wvt   = (const float*)d_in[7];   // w_v_spat (64,64)
  const float* wproj = (const float*)d_in[10];  // w_proj   (64,64)
  float* out = (float*)d_out;

  fused_hsattn<<<HW / PT, 256, 0, stream>>>(x, illu, wvs, wvt, wproj, out);
}

// Round 5
// 203.273 us; speedup vs baseline: 1.0188x; 1.0188x over previous
//
#include <hip/hip_runtime.h>

// y[b,o,p] = sum_c wproj[o,c] * illu[b,c,p] * (sum_i wmix[c,i]*x[b,i,p])
// (attention collapses: DIM==HEADS==64 => softmax over singleton == 1.0;
//  0.6/0.4 output mix commutes onto the weights: wmix = .6*wvs + .4*wvt)
//
// R11: chunk-size probe. R10 refuted aggregate-order camping (cleanest
// traffic ever, 136MB, yet 77us). Seven variants, all 72-79us, share ONE
// untested invariant: per-instruction footprints of 256B chunks at 256KB
// stride (64-px tiles => 4 channel-rows x 256B per wave-load). This round:
// 128-px tiles + float4 lane-contiguous staging -> 512B contiguous chunks
// (2 rows/inst), through LDS:
//   - x staged transposed into XT[p][c] bf16 (stride 68, same fragment
//     reads / MFMA mapping / u'-bounce-in-place as R9/R10 -> same absmax),
//   - illu staged fp32 into ILS[c][p] (stride 132, conflict-spread),
//   - stores unchanged in form, but each 128B line now completes within a
//     single wave (n-tiles 0+1 cover both halves) -> no cross-wave merging.
// T14 kept: t+1's 16 float4 loads issue right after S1, fly over compute.
// LDS 67KB -> 2 blocks/CU; grid 512 persistent x TPB=4 (weights once).
// If this nulls (~72-77us), chunk-size theory dies and the pattern floor
// stands; if it works, expect ~50-60us and push to 1KB chunks next.

#define HW    65536
#define CHHW  (64 * 65536)
#define PT    128            // pixels per tile
#define SXT   68             // XT/WM/WP row stride (shorts): 136B, 8B-aligned
#define SIL   132            // ILS row stride (floats): bank-spread
#define TPB   4              // tiles per block; grid = 2048/TPB = 512

typedef short s4_t __attribute__((ext_vector_type(4)));
typedef short s8_t __attribute__((ext_vector_type(8)));
typedef float f4_t __attribute__((ext_vector_type(4)));

static __device__ __forceinline__ unsigned short f2bf(float f) {
  unsigned u = __float_as_uint(f);
  return (unsigned short)((u + 0x7fffu + ((u >> 16) & 1u)) >> 16);  // RNE
}
static __device__ __forceinline__ s8_t ld8(const unsigned short* p) {
  s4_t lo = *(const s4_t*)p;        // rows 8B-aligned: 2x ds_read_b64
  s4_t hi = *(const s4_t*)(p + 4);
  s8_t r = {lo[0], lo[1], lo[2], lo[3], hi[0], hi[1], hi[2], hi[3]};
  return r;
}

__global__ __launch_bounds__(256, 2) void fused_hsattn(
    const float* __restrict__ x, const float* __restrict__ illu,
    const float* __restrict__ wvs, const float* __restrict__ wvt,
    const float* __restrict__ wproj, float* __restrict__ out) {
  __shared__ __align__(16) unsigned short WM[64 * SXT];  // 8.5 KB wmix
  __shared__ __align__(16) unsigned short WP[64 * SXT];  // 8.5 KB wproj
  __shared__ __align__(16) unsigned short XT[PT * SXT];  // 17.4 KB x^T/u'^T
  __shared__ __align__(16) float ILS[64 * SIL];          // 33.8 KB illu [c][p]

  const int tid  = threadIdx.x;
  const int lane = tid & 63;
  const int wv   = tid >> 6;
  const int n15  = lane & 15;
  const int q    = lane >> 4;

  // staging geometry: one float4 wave-load = 2 channel-rows x 512B contig.
  const int ch0 = wv * 16 + (lane >> 5);   // +2*it -> wave covers 16 channels
  const int pxl = (lane & 31) * 4;         // 4 consecutive pixels per lane

  // ---- (1) weight loads FIRST (L2-hot after wave 1)
  f4_t wa[4], wb[4], wc[4];
#pragma unroll
  for (int it = 0; it < 4; ++it) {
    int j4 = (it * 256 + tid) * 4;
    wa[it] = *(const f4_t*)(wvs + j4);
    wb[it] = *(const f4_t*)(wvt + j4);
    wc[it] = *(const f4_t*)(wproj + j4);
  }

  // ---- (2) tile-0 loads -> regs (512B-contiguous chunks)
  f4_t xr[8], ir[8];
  {
    const int g    = blockIdx.x * TPB;
    const int base = (g >> 9) * CHHW + ((g & 511) << 7);
#pragma unroll
    for (int it = 0; it < 8; ++it) {
      const int off = base + (ch0 + 2 * it) * HW + pxl;
      xr[it] = *(const f4_t*)(x + off);
      ir[it] = *(const f4_t*)(illu + off);
    }
  }

  // ---- (3) weights -> LDS (published by S1 of t=0)
#pragma unroll
  for (int it = 0; it < 4; ++it) {
    int idx = it * 256 + tid;
    int r = idx >> 4, c4 = (idx & 15) * 4;
    s4_t m, w;
#pragma unroll
    for (int j = 0; j < 4; ++j) {
      m[j] = (short)f2bf(0.6f * wa[it][j] + 0.4f * wb[it][j]);
      w[j] = (short)f2bf(wc[it][j]);
    }
    *(s4_t*)(WM + r * SXT + c4) = m;
    *(s4_t*)(WP + r * SXT + c4) = w;
  }

  // ---- (4) tile loop
#pragma unroll
  for (int t = 0; t < TPB; ++t) {
    const int g    = blockIdx.x * TPB + t;
    const int base = (g >> 9) * CHHW + ((g & 511) << 7);

    // publish tile t: x -> XT[p][c] bf16 (transpose), illu -> ILS[c][p] f32
#pragma unroll
    for (int it = 0; it < 8; ++it) {
      const int ch = ch0 + 2 * it;
      f4_t v = xr[it];
#pragma unroll
      for (int j = 0; j < 4; ++j)
        XT[(pxl + j) * SXT + ch] = f2bf(v[j]);
      *(f4_t*)(ILS + ch * SIL + pxl) = ir[it];
    }
    __syncthreads();                        // S1: tile t (and WM/WP) visible

    // T14: issue t+1 loads now; they fly over the whole compute phase
    if (t + 1 < TPB) {
      const int g2 = g + 1;
      const int b2 = (g2 >> 9) * CHHW + ((g2 & 511) << 7);
#pragma unroll
      for (int it = 0; it < 8; ++it) {
        const int off = b2 + (ch0 + 2 * it) * HW + pxl;
        xr[it] = *(const f4_t*)(x + off);
        ir[it] = *(const f4_t*)(illu + off);
      }
    }

    // compute: wave owns pixels [wv*32, wv*32+32) -> 2 n-tiles of 16
#pragma unroll
    for (int nt = 0; nt < 2; ++nt) {
      const int pr = wv * 32 + nt * 16;     // wave-private XT rows
      unsigned short* xrow = XT + (pr + n15) * SXT;

      // phase 1: u = wmix * x
      f4_t acc[4];
#pragma unroll
      for (int i = 0; i < 4; ++i) acc[i] = (f4_t){0.f, 0.f, 0.f, 0.f};
#pragma unroll
      for (int kc = 0; kc < 2; ++kc) {
        s8_t B = ld8(xrow + kc * 32 + q * 8);
#pragma unroll
        for (int mt = 0; mt < 4; ++mt) {
          s8_t A = ld8(WM + (mt * 16 + n15) * SXT + kc * 32 + q * 8);
          acc[mt] = __builtin_amdgcn_mfma_f32_16x16x32_bf16(A, B, acc[mt], 0, 0, 0);
        }
      }

      // gate with illu (LDS f32), overwrite u'^T in place (same-wave rows;
      // all phase-1 ds_reads precede these ds_writes in program order)
#pragma unroll
      for (int mt = 0; mt < 4; ++mt) {
        s4_t h;
#pragma unroll
        for (int r = 0; r < 4; ++r) {
          const int c = mt * 16 + q * 4 + r;
          h[r] = (short)f2bf(acc[mt][r] * ILS[c * SIL + pr + n15]);
        }
        *(s4_t*)(xrow + mt * 16 + q * 4) = h;
      }

      // phase 2: y = wproj * u'
      f4_t acc2[4];
#pragma unroll
      for (int i = 0; i < 4; ++i) acc2[i] = (f4_t){0.f, 0.f, 0.f, 0.f};
#pragma unroll
      for (int kc = 0; kc < 2; ++kc) {
        s8_t B = ld8(xrow + kc * 32 + q * 8);
#pragma unroll
        for (int mt = 0; mt < 4; ++mt) {
          s8_t A = ld8(WP + (mt * 16 + n15) * SXT + kc * 32 + q * 8);
          acc2[mt] = __builtin_amdgcn_mfma_f32_16x16x32_bf16(A, B, acc2[mt], 0, 0, 0);
        }
      }

      // store: both 64B halves of each 128B line come from THIS wave
      // (nt=0 -> px 0-15, nt=1 -> px 16-31 of the wave's 32-px window)
#pragma unroll
      for (int mt = 0; mt < 4; ++mt) {
        float* op = out + base + (mt * 16 + q * 4) * HW + pr + n15;
        f4_t a = acc2[mt];
#pragma unroll
        for (int r = 0; r < 4; ++r) op[r * HW] = a[r];
      }
    }
    __syncthreads();                        // S2: safe to restage XT/ILS
  }
}

extern "C" void kernel_launch(void* const* d_in, const int* in_sizes, int n_in,
                              void* d_out, int out_size, void* d_ws, size_t ws_size,
                              hipStream_t stream) {
  const float* x     = (const float*)d_in[0];   // (4,64,256,256)
  const float* illu  = (const float*)d_in[1];   // (4,64,256,256)
  const float* wvs   = (const float*)d_in[4];   // w_v_spec (64,64)
  const float* wvt   = (const float*)d_in[7];   // w_v_spat (64,64)
  const float* wproj = (const float*)d_in[10];  // w_proj   (64,64)
  float* out = (float*)d_out;

  // 2048 tiles (512 per image x 4 images) / TPB = 512 blocks, 2 per CU
  fused_hsattn<<<(4 * (HW / PT)) / TPB, 256, 0, stream>>>(x, illu, wvs, wvt,
                                                          wproj, out);
}